// Round 7
// baseline (294.859 us; speedup 1.0000x reference)
//
#include <hip/hip_runtime.h>
#include <hip/hip_bf16.h>

#define BB 8
#define NN 2048
#define DD 128

typedef __attribute__((ext_vector_type(8))) __bf16 bf16x8;
typedef __attribute__((ext_vector_type(4))) float f32x4;
typedef __attribute__((ext_vector_type(4))) int   i32x4;

static __device__ __forceinline__ unsigned short f2bf(float f) {
    union { float f; unsigned u; } v; v.f = f;
    unsigned r = (v.u + 0x7FFFu + ((v.u >> 16) & 1u)) >> 16;
    return (unsigned short)r;
}
static __device__ __forceinline__ float bf2f(unsigned short b) {
    union { unsigned u; float f; } v; v.u = ((unsigned)b) << 16;
    return v.f;
}

// ---------------------------------------------------------------------------
// kernP3 (R6-audited, carried): Ptilde bit-pack.
//  * ROW SKIP: mask_i==0 rows -> scale=pdm=0, punct row never read. Stale pk
//    bits are unobservable: bit-expansion yields only {0,1.0f} bf16 (finite),
//    and kernC multiplies by scale=0 -> exact 0, matching reference
//    (graph row all-zero -> agg=0, nbr_f=1).
//  * word-per-lane: lane j packs its own 32 contiguous cols (8 independent
//    dwordx4 loads, no cross-lane shfl in hot loop, 256B coalesced store).
//    Layout identical to ballot version: word w bit p <-> col w*32+p.
//  Blocks >= 2048: weight f32->bf16 conversion (wsb/wpb), same f2bf values
//  as the original in-kernel conversion -> bit-identical numerics.
// ---------------------------------------------------------------------------
__global__ __launch_bounds__(256) void kernP3(
    const int* __restrict__ punct, const int* __restrict__ mask,
    const float* __restrict__ w_self, const float* __restrict__ w_punct,
    unsigned* __restrict__ pk, float* __restrict__ scale_g, float* __restrict__ pdm_g,
    unsigned short* __restrict__ wsb, unsigned short* __restrict__ wpb)
{
    const int bid = blockIdx.x;
    const int t = threadIdx.x;

    if (bid >= 2048) {   // weight conversion tail
        const int cb = bid - 2048;
        const float* src = (cb < 8) ? w_self : w_punct;
        unsigned short* dst = (cb < 8) ? wsb : wpb;
        const size_t i0 = (size_t)(cb & 7) * 2048 + (size_t)t * 8;
        f32x4 a = *(const f32x4*)(src + i0);
        f32x4 c = *(const f32x4*)(src + i0 + 4);
        unsigned q0 = f2bf(a.x) | ((unsigned)f2bf(a.y) << 16);
        unsigned q1 = f2bf(a.z) | ((unsigned)f2bf(a.w) << 16);
        unsigned q2 = f2bf(c.x) | ((unsigned)f2bf(c.y) << 16);
        unsigned q3 = f2bf(c.z) | ((unsigned)f2bf(c.w) << 16);
        i32x4 pw = {(int)q0, (int)q1, (int)q2, (int)q3};
        *(i32x4*)(dst + i0) = pw;
        return;
    }

    const int wave = t >> 6, lane = t & 63;
    const int row0 = bid * 8 + wave * 2;            // 2 rows per wave
    const int b = row0 >> 11;                       // batch uniform per block
    const int* mrow = mask + (size_t)b * NN;

    // mask word for this lane: columns [lane*32, lane*32+32)
    unsigned mw = 0;
    #pragma unroll
    for (int q = 0; q < 8; ++q) {
        i32x4 m = *(const i32x4*)(mrow + lane * 32 + q * 4);
        unsigned nib = (m.x & 1) | ((m.y & 1) << 1) | ((m.z & 1) << 2) | ((m.w & 1) << 3);
        mw |= nib << (4 * q);
    }

    #pragma unroll
    for (int r = 0; r < 2; ++r) {
        const int row = row0 + r;
        const int i = row & (NN - 1);               // diagonal column
        const int mi = mrow[i];                     // wave-uniform
        if (mi == 0) {                              // ROW SKIP (content dead)
            if (lane == 0) { scale_g[row] = 0.f; pdm_g[row] = 0.f; }
            continue;
        }
        const int* prow = punct + (size_t)row * NN;
        i32x4 v[8];
        #pragma unroll
        for (int q = 0; q < 8; ++q)                 // 8 independent 16B loads
            v[q] = *(const i32x4*)(prow + lane * 32 + q * 4);
        unsigned wd = 0;
        #pragma unroll
        for (int q = 0; q < 8; ++q) {
            unsigned nib = (v[q].x & 1) | ((v[q].y & 1) << 1)
                         | ((v[q].z & 1) << 2) | ((v[q].w & 1) << 3);
            wd |= nib << (4 * q);
        }
        wd &= mw;
        pk[(size_t)row * 64 + lane] = wd;           // coalesced 256B store

        int acc = __popc(wd);
        if ((i >> 5) == lane) acc += (int)((wd >> (i & 31)) & 1u) << 16;
        #pragma unroll
        for (int o = 32; o > 0; o >>= 1) acc += __shfl_xor(acc, o, 64);
        if (lane == 0) {
            const int nall = acc & 0xFFFF;
            const int pd   = acc >> 16;             // masked diagonal
            const int nbr  = nall - pd;
            scale_g[row] = 1.f / (float)(nbr < 1 ? 1 : nbr);
            pdm_g[row]   = (float)pd;
        }
    }
}

// ---------------------------------------------------------------------------
// kernB body (R0-proven structure): per 64-row tile, MFMA GEMMs
// si = x@W_self^T + b_self, infop = x@W_punct^T; fused dw = sigmoid(x.w_nw
// + b_nw); writes si f32, yhat = dw*infop bf16 in [n][e] and transposed
// [e][n]. Weights come preconverted (wsb/wpb from kernP3) for BOTH steps.
// ---------------------------------------------------------------------------
static __device__ __forceinline__ void kernB_body(
    int n0, const float* __restrict__ x,
    const float* __restrict__ w_nw,  const float* __restrict__ b_nw,
    const unsigned short* __restrict__ wsb, const float* __restrict__ b_self,
    const unsigned short* __restrict__ wpb,
    float* __restrict__ si_out,
    unsigned short* __restrict__ yne_out,   // [B*N][D] bf16
    unsigned short* __restrict__ yT_out,    // [B][D][N] bf16
    float* __restrict__ aw_out)             // + step*N already applied
{
    __shared__ unsigned short xt[64*32];
    __shared__ unsigned short wst[128*32];
    __shared__ unsigned short wpt[128*32];
    __shared__ float wnw_l[DD];
    __shared__ float red[256];
    __shared__ float dw_l[64];
    __shared__ unsigned short ytl[128*72];

    const int t  = threadIdx.x;
    const int b  = n0 >> 11;
    const int nb = n0 & (NN - 1);

    if (t < DD) wnw_l[t] = w_nw[t];
    __syncthreads();

    const int wave = t >> 6, lane = t & 63;
    const int wm = wave >> 1, wn = wave & 1;
    const int quad = lane >> 4, l16 = lane & 15;

    const int n_loc = t >> 2, dq = t & 3;
    const int we = t >> 1,   wh = t & 1;

    f32x4 accs[2][4] = {}; f32x4 accp[2][4] = {};
    float dwpart = 0.f;

    #pragma unroll
    for (int kk = 0; kk < 4; ++kk) {
        const int k0 = kk * 32;
        {
            const float* xs = x + (size_t)(n0 + n_loc) * DD + k0 + dq * 8;
            f32x4 a = *(const f32x4*)xs;
            f32x4 c = *(const f32x4*)(xs + 4);
            const float* wv = &wnw_l[k0 + dq * 8];
            dwpart += a.x*wv[0] + a.y*wv[1] + a.z*wv[2] + a.w*wv[3]
                    + c.x*wv[4] + c.y*wv[5] + c.z*wv[6] + c.w*wv[7];
            unsigned q0 = f2bf(a.x) | ((unsigned)f2bf(a.y) << 16);
            unsigned q1 = f2bf(a.z) | ((unsigned)f2bf(a.w) << 16);
            unsigned q2 = f2bf(c.x) | ((unsigned)f2bf(c.y) << 16);
            unsigned q3 = f2bf(c.z) | ((unsigned)f2bf(c.w) << 16);
            i32x4 pw = {(int)q0,(int)q1,(int)q2,(int)q3};
            *(i32x4*)&xt[n_loc*32 + dq*8] = pw;
        }
        {
            const unsigned short* s1 = wsb + (size_t)we * DD + k0 + wh*16;
            const unsigned short* s2 = wpb + (size_t)we * DD + k0 + wh*16;
            i32x4 a0 = *(const i32x4*)s1;
            i32x4 a1 = *(const i32x4*)(s1 + 8);
            *(i32x4*)&wst[we*32 + wh*16]     = a0;
            *(i32x4*)&wst[we*32 + wh*16 + 8] = a1;
            i32x4 c0 = *(const i32x4*)s2;
            i32x4 c1 = *(const i32x4*)(s2 + 8);
            *(i32x4*)&wpt[we*32 + wh*16]     = c0;
            *(i32x4*)&wpt[we*32 + wh*16 + 8] = c1;
        }
        __syncthreads();
        bf16x8 af[2], bs[4], bp[4];
        #pragma unroll
        for (int mt = 0; mt < 2; ++mt)
            af[mt] = *(const bf16x8*)&xt[(wm*32 + mt*16 + l16)*32 + quad*8];
        #pragma unroll
        for (int nt = 0; nt < 4; ++nt) {
            const int er = wn*64 + nt*16 + l16;
            bs[nt] = *(const bf16x8*)&wst[er*32 + quad*8];
            bp[nt] = *(const bf16x8*)&wpt[er*32 + quad*8];
        }
        #pragma unroll
        for (int mt = 0; mt < 2; ++mt)
            #pragma unroll
            for (int nt = 0; nt < 4; ++nt) {
                accs[mt][nt] = __builtin_amdgcn_mfma_f32_16x16x32_bf16(af[mt], bs[nt], accs[mt][nt], 0, 0, 0);
                accp[mt][nt] = __builtin_amdgcn_mfma_f32_16x16x32_bf16(af[mt], bp[nt], accp[mt][nt], 0, 0, 0);
            }
        __syncthreads();
    }

    red[t] = dwpart;
    __syncthreads();
    if (t < 64) {
        float s = red[4*t] + red[4*t+1] + red[4*t+2] + red[4*t+3] + b_nw[0];
        float dv = 1.f / (1.f + __expf(-s));
        dw_l[t] = dv;
        aw_out[(size_t)b * 2 * NN + nb + t] = dv;
    }
    __syncthreads();

    #pragma unroll
    for (int mt = 0; mt < 2; ++mt) {
        #pragma unroll
        for (int nt = 0; nt < 4; ++nt) {
            const int e = wn*64 + nt*16 + l16;
            const float bsv = b_self[e];
            #pragma unroll
            for (int r = 0; r < 4; ++r) {
                const int nl = wm*32 + mt*16 + quad*4 + r;
                const size_t idx = (size_t)(n0 + nl) * DD + e;
                si_out[idx] = accs[mt][nt][r] + bsv;
                const float yv = dw_l[nl] * accp[mt][nt][r];
                const unsigned short ub = f2bf(yv);
                yne_out[idx] = ub;
                ytl[e*72 + nl] = ub;
            }
        }
    }
    __syncthreads();
    {
        const int e = t >> 1, half = t & 1;
        const i32x4* src = (const i32x4*)&ytl[e*72 + half*32];
        i32x4 v0 = src[0], v1 = src[1], v2 = src[2], v3 = src[3];
        i32x4* dst = (i32x4*)(yT_out + (size_t)(b*DD + e) * NN + nb + half*32);
        dst[0] = v0; dst[1] = v1; dst[2] = v2; dst[3] = v3;
    }
}

__global__ __launch_bounds__(256) void kernB(
    const float* __restrict__ x,
    const unsigned short* __restrict__ wsb, const unsigned short* __restrict__ wpb,
    const float* __restrict__ w_nw, const float* __restrict__ b_nw,
    const float* __restrict__ b_self,
    float* __restrict__ si, unsigned short* __restrict__ yne,
    unsigned short* __restrict__ yT, float* __restrict__ aw_s)
{
    kernB_body(blockIdx.x * 64, x, w_nw, b_nw, wsb, b_self, wpb,
               si, yne, yT, aw_s);
}

// ---------------------------------------------------------------------------
// kernC3: agg = Ptilde @ yhat. Round-7 fix of R6's grid bug (R6 launched
// 1024 blocks whose indexing decoded i0 up to 4032 >= NN -> cross-batch
// row aliasing + races -> absmax fail). Now: 32-row x 64-e tiles, 128 thr
// (2 waves), grid = 8 batches x 64 row-tiles x 2 e-halves = 1024, BIJECTIVE
// (i0 max 2016, +row max 31 = 2047). 4 blocks/CU x 2 waves = 2 waves/SIMD
// TLP on the dependent-load K chain. e-split does not duplicate yT panel
// reads per e-half; row-split re-reads are L2-resident under the XCD-aware
// batch mapping (b = blk&7, 1024%8==0).
// Epilogue: x = relu(si + scale*(acc - pdm*yhat_i)).
// ---------------------------------------------------------------------------
__global__ __launch_bounds__(128) void kernC3(
    const unsigned* __restrict__ pk,        // [B*N][64] packed bits
    const float* __restrict__ scale_g, const float* __restrict__ pdm_g,
    const unsigned short* __restrict__ yT,  // [B][D][N] bf16
    const float* __restrict__ si,           // [B*N][D]
    const unsigned short* __restrict__ yne, // [B*N][D] bf16
    float* __restrict__ x_out)              // [B*N][D]
{
    __shared__ unsigned pPk[32 * 68];       // 32 rows x 64 words, pad 68
    __shared__ float scale_l[32];
    __shared__ float pdm_l[32];

    const int t   = threadIdx.x;
    const int b   = blockIdx.x & 7;         // XCD-aware batch mapping
    const int idx = blockIdx.x >> 3;        // 0..127 = 64 row-tiles x 2 e-halves
    const int i0  = (idx >> 1) * 32;        // 0..2016
    const int e0  = (idx & 1) * 64;         // 0 or 64
    const size_t rg0 = (size_t)b * NN + i0;

    #pragma unroll
    for (int r = 0; r < 4; ++r) {
        const int u   = r * 128 + t;        // 0..511 = 32 rows x 16 chunks
        const int row = u >> 4;
        const int wq  = (u & 15) * 4;
        i32x4 v = *(const i32x4*)(pk + (rg0 + row) * 64 + wq);
        *(i32x4*)&pPk[row * 68 + wq] = v;
    }
    if (t < 32) {
        scale_l[t] = scale_g[rg0 + t];
        pdm_l[t]   = pdm_g[rg0 + t];
    }
    __syncthreads();

    const int wn = t >> 6, lane = t & 63;   // wn in {0,1}
    const int quad = lane >> 4, l16 = lane & 15;
    const unsigned short* yTb = yT + (size_t)b * DD * NN;

    f32x4 acc[2][2] = {};

    #pragma unroll 4
    for (int kk = 0; kk < 64; ++kk) {
        bf16x8 bfr[2];
        #pragma unroll
        for (int nt = 0; nt < 2; ++nt) {
            const int e = e0 + wn*32 + nt*16 + l16;
            bfr[nt] = *(const bf16x8*)(yTb + (size_t)e * NN + kk*32 + quad*8);
        }
        bf16x8 af[2];
        #pragma unroll
        for (int mt = 0; mt < 2; ++mt) {
            const unsigned w = pPk[(mt*16 + l16) * 68 + kk];
            const unsigned by = (w >> (quad * 8)) & 0xFFu;
            i32x4 ex;
            ex.x = ((by &   1u) ? 0x3F80 : 0) | ((by &   2u) ? 0x3F800000 : 0);
            ex.y = ((by &   4u) ? 0x3F80 : 0) | ((by &   8u) ? 0x3F800000 : 0);
            ex.z = ((by &  16u) ? 0x3F80 : 0) | ((by &  32u) ? 0x3F800000 : 0);
            ex.w = ((by &  64u) ? 0x3F80 : 0) | ((by & 128u) ? 0x3F800000 : 0);
            union { i32x4 i; bf16x8 h; } cv; cv.i = ex;
            af[mt] = cv.h;
        }
        #pragma unroll
        for (int mt = 0; mt < 2; ++mt)
            #pragma unroll
            for (int nt = 0; nt < 2; ++nt)
                acc[mt][nt] = __builtin_amdgcn_mfma_f32_16x16x32_bf16(af[mt], bfr[nt], acc[mt][nt], 0, 0, 0);
    }

    #pragma unroll
    for (int mt = 0; mt < 2; ++mt) {
        #pragma unroll
        for (int nt = 0; nt < 2; ++nt) {
            const int e = e0 + wn*32 + nt*16 + l16;
            #pragma unroll
            for (int r = 0; r < 4; ++r) {
                const int row = mt*16 + quad*4 + r;
                const size_t idx2 = (rg0 + row) * DD + e;
                const float yv = bf2f(yne[idx2]);
                float v = si[idx2] + scale_l[row] * (acc[mt][nt][r] - pdm_l[row] * yv);
                x_out[idx2] = fmaxf(v, 0.f);
            }
        }
    }
}

extern "C" void kernel_launch(void* const* d_in, const int* in_sizes, int n_in,
                              void* d_out, int out_size, void* d_ws, size_t ws_size,
                              hipStream_t stream) {
    const float* node   = (const float*)d_in[0];
    const int*   mask   = (const int*)  d_in[1];
    const int*   punct  = (const int*)  d_in[2];
    const float* w_nw   = (const float*)d_in[3];
    const float* b_nw   = (const float*)d_in[4];
    const float* w_self = (const float*)d_in[5];
    const float* b_self = (const float*)d_in[6];
    const float* w_punct= (const float*)d_in[7];

    float* xout = (float*)d_out;
    float* aw   = xout + (size_t)BB * NN * DD;

    char* w = (char*)d_ws;
    float*          si   = (float*)w;                               // 8 MB
    unsigned short* yne  = (unsigned short*)(w + (8u  << 20));      // 4 MB
    unsigned short* yT   = (unsigned short*)(w + (12u << 20));      // 4 MB
    unsigned*       pk   = (unsigned*)(w + (16u << 20));            // 4 MB
    float*          scl  = (float*)(w + (20u << 20));               // 64 KB
    float*          pdm  = (float*)(w + (20u << 20) + (64u << 10)); // 64 KB
    unsigned short* wsb  = (unsigned short*)(w + (21u << 20));      // 32 KB
    unsigned short* wpb  = (unsigned short*)(w + (21u << 20) + (32u << 10)); // 32 KB

    kernP3<<<dim3(2064), dim3(256), 0, stream>>>(punct, mask, w_self, w_punct,
                                                 pk, scl, pdm, wsb, wpb);
    kernB <<<dim3(256),  dim3(256), 0, stream>>>(node, wsb, wpb, w_nw, b_nw,
                                                 b_self, si, yne, yT, aw);
    kernC3<<<dim3(1024), dim3(128), 0, stream>>>(pk, scl, pdm, yT, si, yne, xout);
    kernB <<<dim3(256),  dim3(256), 0, stream>>>(xout, wsb, wpb, w_nw, b_nw,
                                                 b_self, si, yne, yT, aw + NN);
    kernC3<<<dim3(1024), dim3(128), 0, stream>>>(pk, scl, pdm, yT, si, yne, xout);
}

// Round 8
// 268.017 us; speedup vs baseline: 1.1002x; 1.1002x over previous
//
#include <hip/hip_runtime.h>
#include <hip/hip_bf16.h>

#define BB 8
#define NN 2048
#define DD 128

typedef __attribute__((ext_vector_type(8))) __bf16 bf16x8;
typedef __attribute__((ext_vector_type(4))) float f32x4;
typedef __attribute__((ext_vector_type(4))) int   i32x4;

static __device__ __forceinline__ unsigned short f2bf(float f) {
    union { float f; unsigned u; } v; v.f = f;
    unsigned r = (v.u + 0x7FFFu + ((v.u >> 16) & 1u)) >> 16;
    return (unsigned short)r;
}
static __device__ __forceinline__ float bf2f(unsigned short b) {
    union { unsigned u; float f; } v; v.u = ((unsigned)b) << 16;
    return v.f;
}

// ---------------------------------------------------------------------------
// kernP3 (carried from R7, passed): Ptilde bit-pack with row-skip +
// word-per-lane. Blocks >= 2048: weight f32->bf16 conversion.
// ---------------------------------------------------------------------------
__global__ __launch_bounds__(256) void kernP3(
    const int* __restrict__ punct, const int* __restrict__ mask,
    const float* __restrict__ w_self, const float* __restrict__ w_punct,
    unsigned* __restrict__ pk, float* __restrict__ scale_g, float* __restrict__ pdm_g,
    unsigned short* __restrict__ wsb, unsigned short* __restrict__ wpb)
{
    const int bid = blockIdx.x;
    const int t = threadIdx.x;

    if (bid >= 2048) {   // weight conversion tail
        const int cb = bid - 2048;
        const float* src = (cb < 8) ? w_self : w_punct;
        unsigned short* dst = (cb < 8) ? wsb : wpb;
        const size_t i0 = (size_t)(cb & 7) * 2048 + (size_t)t * 8;
        f32x4 a = *(const f32x4*)(src + i0);
        f32x4 c = *(const f32x4*)(src + i0 + 4);
        unsigned q0 = f2bf(a.x) | ((unsigned)f2bf(a.y) << 16);
        unsigned q1 = f2bf(a.z) | ((unsigned)f2bf(a.w) << 16);
        unsigned q2 = f2bf(c.x) | ((unsigned)f2bf(c.y) << 16);
        unsigned q3 = f2bf(c.z) | ((unsigned)f2bf(c.w) << 16);
        i32x4 pw = {(int)q0, (int)q1, (int)q2, (int)q3};
        *(i32x4*)(dst + i0) = pw;
        return;
    }

    const int wave = t >> 6, lane = t & 63;
    const int row0 = bid * 8 + wave * 2;            // 2 rows per wave
    const int b = row0 >> 11;
    const int* mrow = mask + (size_t)b * NN;

    unsigned mw = 0;
    #pragma unroll
    for (int q = 0; q < 8; ++q) {
        i32x4 m = *(const i32x4*)(mrow + lane * 32 + q * 4);
        unsigned nib = (m.x & 1) | ((m.y & 1) << 1) | ((m.z & 1) << 2) | ((m.w & 1) << 3);
        mw |= nib << (4 * q);
    }

    #pragma unroll
    for (int r = 0; r < 2; ++r) {
        const int row = row0 + r;
        const int i = row & (NN - 1);               // diagonal column
        const int mi = mrow[i];                     // wave-uniform
        if (mi == 0) {                              // ROW SKIP (content dead)
            if (lane == 0) { scale_g[row] = 0.f; pdm_g[row] = 0.f; }
            continue;
        }
        const int* prow = punct + (size_t)row * NN;
        i32x4 v[8];
        #pragma unroll
        for (int q = 0; q < 8; ++q)
            v[q] = *(const i32x4*)(prow + lane * 32 + q * 4);
        unsigned wd = 0;
        #pragma unroll
        for (int q = 0; q < 8; ++q) {
            unsigned nib = (v[q].x & 1) | ((v[q].y & 1) << 1)
                         | ((v[q].z & 1) << 2) | ((v[q].w & 1) << 3);
            wd |= nib << (4 * q);
        }
        wd &= mw;
        pk[(size_t)row * 64 + lane] = wd;

        int acc = __popc(wd);
        if ((i >> 5) == lane) acc += (int)((wd >> (i & 31)) & 1u) << 16;
        #pragma unroll
        for (int o = 32; o > 0; o >>= 1) acc += __shfl_xor(acc, o, 64);
        if (lane == 0) {
            const int nall = acc & 0xFFFF;
            const int pd   = acc >> 16;
            const int nbr  = nall - pd;
            scale_g[row] = 1.f / (float)(nbr < 1 ? 1 : nbr);
            pdm_g[row]   = (float)pd;
        }
    }
}

// ---------------------------------------------------------------------------
// kernB body (R0-proven GEMM structure). Round-8 delta: DIAG FOLD —
// si' = x@Ws^T + b_self - scale*pdm*round_bf16(yhat)  (per row), so kernC
// never reads yne (yne dropped entirely). Same yhat rounding point; only
// scale*(acc - pdm*y) -> scale*acc - (scale*pdm*y) re-association.
// ---------------------------------------------------------------------------
static __device__ __forceinline__ void kernB_body(
    int n0, const float* __restrict__ x,
    const float* __restrict__ w_nw,  const float* __restrict__ b_nw,
    const unsigned short* __restrict__ wsb, const float* __restrict__ b_self,
    const unsigned short* __restrict__ wpb,
    const float* __restrict__ scale_g, const float* __restrict__ pdm_g,
    float* __restrict__ si_out,             // si' (diag-folded)
    unsigned short* __restrict__ yT_out,    // [B][D][N] bf16
    float* __restrict__ aw_out)             // + step*N already applied
{
    __shared__ unsigned short xt[64*32];
    __shared__ unsigned short wst[128*32];
    __shared__ unsigned short wpt[128*32];
    __shared__ float wnw_l[DD];
    __shared__ float red[256];
    __shared__ float dw_l[64];
    __shared__ float scl_l[64];
    __shared__ float pdm_l[64];
    __shared__ unsigned short ytl[128*72];

    const int t  = threadIdx.x;
    const int b  = n0 >> 11;
    const int nb = n0 & (NN - 1);

    if (t < DD) wnw_l[t] = w_nw[t];
    if (t >= 128 && t < 192) { scl_l[t-128] = scale_g[n0 + t - 128]; }
    if (t >= 192)            { pdm_l[t-192] = pdm_g[n0 + t - 192]; }
    __syncthreads();

    const int wave = t >> 6, lane = t & 63;
    const int wm = wave >> 1, wn = wave & 1;
    const int quad = lane >> 4, l16 = lane & 15;

    const int n_loc = t >> 2, dq = t & 3;
    const int we = t >> 1,   wh = t & 1;

    f32x4 accs[2][4] = {}; f32x4 accp[2][4] = {};
    float dwpart = 0.f;

    #pragma unroll
    for (int kk = 0; kk < 4; ++kk) {
        const int k0 = kk * 32;
        {
            const float* xs = x + (size_t)(n0 + n_loc) * DD + k0 + dq * 8;
            f32x4 a = *(const f32x4*)xs;
            f32x4 c = *(const f32x4*)(xs + 4);
            const float* wv = &wnw_l[k0 + dq * 8];
            dwpart += a.x*wv[0] + a.y*wv[1] + a.z*wv[2] + a.w*wv[3]
                    + c.x*wv[4] + c.y*wv[5] + c.z*wv[6] + c.w*wv[7];
            unsigned q0 = f2bf(a.x) | ((unsigned)f2bf(a.y) << 16);
            unsigned q1 = f2bf(a.z) | ((unsigned)f2bf(a.w) << 16);
            unsigned q2 = f2bf(c.x) | ((unsigned)f2bf(c.y) << 16);
            unsigned q3 = f2bf(c.z) | ((unsigned)f2bf(c.w) << 16);
            i32x4 pw = {(int)q0,(int)q1,(int)q2,(int)q3};
            *(i32x4*)&xt[n_loc*32 + dq*8] = pw;
        }
        {
            const unsigned short* s1 = wsb + (size_t)we * DD + k0 + wh*16;
            const unsigned short* s2 = wpb + (size_t)we * DD + k0 + wh*16;
            i32x4 a0 = *(const i32x4*)s1;
            i32x4 a1 = *(const i32x4*)(s1 + 8);
            *(i32x4*)&wst[we*32 + wh*16]     = a0;
            *(i32x4*)&wst[we*32 + wh*16 + 8] = a1;
            i32x4 c0 = *(const i32x4*)s2;
            i32x4 c1 = *(const i32x4*)(s2 + 8);
            *(i32x4*)&wpt[we*32 + wh*16]     = c0;
            *(i32x4*)&wpt[we*32 + wh*16 + 8] = c1;
        }
        __syncthreads();
        bf16x8 af[2], bs[4], bp[4];
        #pragma unroll
        for (int mt = 0; mt < 2; ++mt)
            af[mt] = *(const bf16x8*)&xt[(wm*32 + mt*16 + l16)*32 + quad*8];
        #pragma unroll
        for (int nt = 0; nt < 4; ++nt) {
            const int er = wn*64 + nt*16 + l16;
            bs[nt] = *(const bf16x8*)&wst[er*32 + quad*8];
            bp[nt] = *(const bf16x8*)&wpt[er*32 + quad*8];
        }
        #pragma unroll
        for (int mt = 0; mt < 2; ++mt)
            #pragma unroll
            for (int nt = 0; nt < 4; ++nt) {
                accs[mt][nt] = __builtin_amdgcn_mfma_f32_16x16x32_bf16(af[mt], bs[nt], accs[mt][nt], 0, 0, 0);
                accp[mt][nt] = __builtin_amdgcn_mfma_f32_16x16x32_bf16(af[mt], bp[nt], accp[mt][nt], 0, 0, 0);
            }
        __syncthreads();
    }

    red[t] = dwpart;
    __syncthreads();
    if (t < 64) {
        float s = red[4*t] + red[4*t+1] + red[4*t+2] + red[4*t+3] + b_nw[0];
        float dv = 1.f / (1.f + __expf(-s));
        dw_l[t] = dv;
        aw_out[(size_t)b * 2 * NN + nb + t] = dv;
    }
    __syncthreads();

    #pragma unroll
    for (int mt = 0; mt < 2; ++mt) {
        #pragma unroll
        for (int nt = 0; nt < 4; ++nt) {
            const int e = wn*64 + nt*16 + l16;
            const float bsv = b_self[e];
            #pragma unroll
            for (int r = 0; r < 4; ++r) {
                const int nl = wm*32 + mt*16 + quad*4 + r;
                const size_t idx = (size_t)(n0 + nl) * DD + e;
                const float yv = dw_l[nl] * accp[mt][nt][r];
                const unsigned short ub = f2bf(yv);
                const float yvr = bf2f(ub);
                si_out[idx] = accs[mt][nt][r] + bsv - scl_l[nl] * pdm_l[nl] * yvr;
                ytl[e*72 + nl] = ub;
            }
        }
    }
    __syncthreads();
    {
        const int e = t >> 1, half = t & 1;
        const i32x4* src = (const i32x4*)&ytl[e*72 + half*32];
        i32x4 v0 = src[0], v1 = src[1], v2 = src[2], v3 = src[3];
        i32x4* dst = (i32x4*)(yT_out + (size_t)(b*DD + e) * NN + nb + half*32);
        dst[0] = v0; dst[1] = v1; dst[2] = v2; dst[3] = v3;
    }
}

__global__ __launch_bounds__(256) void kernB(
    const float* __restrict__ x,
    const unsigned short* __restrict__ wsb, const unsigned short* __restrict__ wpb,
    const float* __restrict__ w_nw, const float* __restrict__ b_nw,
    const float* __restrict__ b_self,
    const float* __restrict__ scale_g, const float* __restrict__ pdm_g,
    float* __restrict__ si, unsigned short* __restrict__ yT,
    float* __restrict__ aw_s)
{
    kernB_body(blockIdx.x * 64, x, w_nw, b_nw, wsb, b_self, wpb,
               scale_g, pdm_g, si, yT, aw_s);
}

// ---------------------------------------------------------------------------
// kernC4: agg = Ptilde @ yhat. Round-8 restructure for MFMA density:
//  * Each wave owns 64 rows x 64 e (nt=4): one bit-expansion feeds 16 MFMA
//    (was 8) -> per-block expansions halve (1024 -> 512).
//  * K split across wave pairs: waves 0,1 = K-half 0 (e-half 0,1); waves
//    2,3 = K-half 1. One-shot LDS partial-sum reduction at the end.
//  * Expansion via shift+mul identity (5 VALU/word, no vcc):
//    w = (((by&1)<<7) + ((by&2)<<22)) * 0x7F  (128*127=0x3F80=bf16 1.0;
//    0x800000*127=0x3F800000).
//  * Diag fold in B -> no yne read; epilogue v = si' + scale*acc.
// grid 256 (b = blk&7 XCD-aware, i0 = (blk>>3)*64 <= 1984: bijective).
// ---------------------------------------------------------------------------
__global__ __launch_bounds__(256) void kernC4(
    const unsigned* __restrict__ pk,        // [B*N][64] packed bits
    const float* __restrict__ scale_g,
    const unsigned short* __restrict__ yT,  // [B][D][N] bf16
    const float* __restrict__ sip,          // [B*N][D] si' (diag-folded)
    float* __restrict__ x_out)              // [B*N][D]
{
    __shared__ unsigned pPk[64 * 68];       // 64 rows x 64 words, pad 68
    __shared__ float scale_l[64];
    __shared__ f32x4 accL[2][16][64];       // [eh][mt*4+nt][lane] partials

    const int t  = threadIdx.x;
    const int b  = blockIdx.x & 7;          // XCD-aware batch mapping
    const int i0 = (blockIdx.x >> 3) * 64;  // 0..1984
    const size_t rg0 = (size_t)b * NN + i0;

    #pragma unroll
    for (int r = 0; r < 4; ++r) {
        const int u   = r * 256 + t;
        const int row = u >> 4;
        const int wq  = (u & 15) * 4;
        i32x4 v = *(const i32x4*)(pk + (rg0 + row) * 64 + wq);
        *(i32x4*)&pPk[row * 68 + wq] = v;
    }
    if (t < 64) scale_l[t] = scale_g[rg0 + t];
    __syncthreads();

    const int wave = t >> 6, lane = t & 63;
    const int kh = wave >> 1, eh = wave & 1;
    const int quad = lane >> 4, l16 = lane & 15;
    const unsigned short* yTb = yT + (size_t)b * DD * NN;

    f32x4 acc[4][4] = {};

    #pragma unroll 4
    for (int ks = 0; ks < 32; ++ks) {
        const int kk = kh * 32 + ks;
        bf16x8 bfr[4];
        #pragma unroll
        for (int nt = 0; nt < 4; ++nt) {
            const int e = eh*64 + nt*16 + l16;
            bfr[nt] = *(const bf16x8*)(yTb + (size_t)e * NN + kk*32 + quad*8);
        }
        bf16x8 af[4];
        #pragma unroll
        for (int mt = 0; mt < 4; ++mt) {
            const unsigned w = pPk[(mt*16 + l16) * 68 + kk];
            const unsigned by = (w >> (quad * 8)) & 0xFFu;
            i32x4 ex;
            ex.x = (int)((((by &   1u) << 7) + ((by &   2u) << 22)) * 0x7Fu);
            ex.y = (int)((((by &   4u) << 5) + ((by &   8u) << 20)) * 0x7Fu);
            ex.z = (int)((((by &  16u) << 3) + ((by &  32u) << 18)) * 0x7Fu);
            ex.w = (int)((((by &  64u) << 1) + ((by & 128u) << 16)) * 0x7Fu);
            union { i32x4 i; bf16x8 h; } cv; cv.i = ex;
            af[mt] = cv.h;
        }
        #pragma unroll
        for (int mt = 0; mt < 4; ++mt)
            #pragma unroll
            for (int nt = 0; nt < 4; ++nt)
                acc[mt][nt] = __builtin_amdgcn_mfma_f32_16x16x32_bf16(af[mt], bfr[nt], acc[mt][nt], 0, 0, 0);
    }

    __syncthreads();          // all K-loops done (pPk no longer needed)
    if (kh == 1) {
        #pragma unroll
        for (int mt = 0; mt < 4; ++mt)
            #pragma unroll
            for (int nt = 0; nt < 4; ++nt)
                accL[eh][mt*4 + nt][lane] = acc[mt][nt];
    }
    __syncthreads();
    if (kh == 0) {
        #pragma unroll
        for (int mt = 0; mt < 4; ++mt) {
            #pragma unroll
            for (int nt = 0; nt < 4; ++nt) {
                f32x4 o = accL[eh][mt*4 + nt][lane];
                const int e = eh*64 + nt*16 + l16;
                #pragma unroll
                for (int r = 0; r < 4; ++r) {
                    const int row = mt*16 + quad*4 + r;
                    const size_t idx = (rg0 + row) * DD + e;
                    float v = sip[idx] + scale_l[row] * (acc[mt][nt][r] + o[r]);
                    x_out[idx] = fmaxf(v, 0.f);
                }
            }
        }
    }
}

extern "C" void kernel_launch(void* const* d_in, const int* in_sizes, int n_in,
                              void* d_out, int out_size, void* d_ws, size_t ws_size,
                              hipStream_t stream) {
    const float* node   = (const float*)d_in[0];
    const int*   mask   = (const int*)  d_in[1];
    const int*   punct  = (const int*)  d_in[2];
    const float* w_nw   = (const float*)d_in[3];
    const float* b_nw   = (const float*)d_in[4];
    const float* w_self = (const float*)d_in[5];
    const float* b_self = (const float*)d_in[6];
    const float* w_punct= (const float*)d_in[7];

    float* xout = (float*)d_out;
    float* aw   = xout + (size_t)BB * NN * DD;

    char* w = (char*)d_ws;
    float*          si   = (float*)w;                               // 8 MB (si')
    unsigned short* yT   = (unsigned short*)(w + (12u << 20));      // 4 MB
    unsigned*       pk   = (unsigned*)(w + (16u << 20));            // 4 MB
    float*          scl  = (float*)(w + (20u << 20));               // 64 KB
    float*          pdm  = (float*)(w + (20u << 20) + (64u << 10)); // 64 KB
    unsigned short* wsb  = (unsigned short*)(w + (21u << 20));      // 32 KB
    unsigned short* wpb  = (unsigned short*)(w + (21u << 20) + (32u << 10)); // 32 KB

    kernP3<<<dim3(2064), dim3(256), 0, stream>>>(punct, mask, w_self, w_punct,
                                                 pk, scl, pdm, wsb, wpb);
    kernB <<<dim3(256),  dim3(256), 0, stream>>>(node, wsb, wpb, w_nw, b_nw,
                                                 b_self, scl, pdm, si, yT, aw);
    kernC4<<<dim3(256),  dim3(256), 0, stream>>>(pk, scl, yT, si, xout);
    kernB <<<dim3(256),  dim3(256), 0, stream>>>(xout, wsb, wpb, w_nw, b_nw,
                                                 b_self, scl, pdm, si, yT, aw + NN);
    kernC4<<<dim3(256),  dim3(256), 0, stream>>>(pk, scl, yT, si, xout);
}

// Round 9
// 258.859 us; speedup vs baseline: 1.1391x; 1.0354x over previous
//
#include <hip/hip_runtime.h>
#include <hip/hip_bf16.h>

#define BB 8
#define NN 2048
#define DD 128

typedef __attribute__((ext_vector_type(8))) __bf16 bf16x8;
typedef __attribute__((ext_vector_type(4))) float f32x4;
typedef __attribute__((ext_vector_type(4))) int   i32x4;

static __device__ __forceinline__ unsigned short f2bf(float f) {
    union { float f; unsigned u; } v; v.f = f;
    unsigned r = (v.u + 0x7FFFu + ((v.u >> 16) & 1u)) >> 16;
    return (unsigned short)r;
}
static __device__ __forceinline__ float bf2f(unsigned short b) {
    union { unsigned u; float f; } v; v.u = ((unsigned)b) << 16;
    return v.f;
}

// ---------------------------------------------------------------------------
// kernP3 (carried from R8, passed): Ptilde bit-pack with row-skip +
// word-per-lane. Blocks >= 2048: weight f32->bf16 conversion.
// ---------------------------------------------------------------------------
__global__ __launch_bounds__(256) void kernP3(
    const int* __restrict__ punct, const int* __restrict__ mask,
    const float* __restrict__ w_self, const float* __restrict__ w_punct,
    unsigned* __restrict__ pk, float* __restrict__ scale_g, float* __restrict__ pdm_g,
    unsigned short* __restrict__ wsb, unsigned short* __restrict__ wpb)
{
    const int bid = blockIdx.x;
    const int t = threadIdx.x;

    if (bid >= 2048) {   // weight conversion tail
        const int cb = bid - 2048;
        const float* src = (cb < 8) ? w_self : w_punct;
        unsigned short* dst = (cb < 8) ? wsb : wpb;
        const size_t i0 = (size_t)(cb & 7) * 2048 + (size_t)t * 8;
        f32x4 a = *(const f32x4*)(src + i0);
        f32x4 c = *(const f32x4*)(src + i0 + 4);
        unsigned q0 = f2bf(a.x) | ((unsigned)f2bf(a.y) << 16);
        unsigned q1 = f2bf(a.z) | ((unsigned)f2bf(a.w) << 16);
        unsigned q2 = f2bf(c.x) | ((unsigned)f2bf(c.y) << 16);
        unsigned q3 = f2bf(c.z) | ((unsigned)f2bf(c.w) << 16);
        i32x4 pw = {(int)q0, (int)q1, (int)q2, (int)q3};
        *(i32x4*)(dst + i0) = pw;
        return;
    }

    const int wave = t >> 6, lane = t & 63;
    const int row0 = bid * 8 + wave * 2;            // 2 rows per wave
    const int b = row0 >> 11;
    const int* mrow = mask + (size_t)b * NN;

    unsigned mw = 0;
    #pragma unroll
    for (int q = 0; q < 8; ++q) {
        i32x4 m = *(const i32x4*)(mrow + lane * 32 + q * 4);
        unsigned nib = (m.x & 1) | ((m.y & 1) << 1) | ((m.z & 1) << 2) | ((m.w & 1) << 3);
        mw |= nib << (4 * q);
    }

    #pragma unroll
    for (int r = 0; r < 2; ++r) {
        const int row = row0 + r;
        const int i = row & (NN - 1);               // diagonal column
        const int mi = mrow[i];                     // wave-uniform
        if (mi == 0) {                              // ROW SKIP (content dead)
            if (lane == 0) { scale_g[row] = 0.f; pdm_g[row] = 0.f; }
            continue;
        }
        const int* prow = punct + (size_t)row * NN;
        i32x4 v[8];
        #pragma unroll
        for (int q = 0; q < 8; ++q)
            v[q] = *(const i32x4*)(prow + lane * 32 + q * 4);
        unsigned wd = 0;
        #pragma unroll
        for (int q = 0; q < 8; ++q) {
            unsigned nib = (v[q].x & 1) | ((v[q].y & 1) << 1)
                         | ((v[q].z & 1) << 2) | ((v[q].w & 1) << 3);
            wd |= nib << (4 * q);
        }
        wd &= mw;
        pk[(size_t)row * 64 + lane] = wd;

        int acc = __popc(wd);
        if ((i >> 5) == lane) acc += (int)((wd >> (i & 31)) & 1u) << 16;
        #pragma unroll
        for (int o = 32; o > 0; o >>= 1) acc += __shfl_xor(acc, o, 64);
        if (lane == 0) {
            const int nall = acc & 0xFFFF;
            const int pd   = acc >> 16;
            const int nbr  = nall - pd;
            scale_g[row] = 1.f / (float)(nbr < 1 ? 1 : nbr);
            pdm_g[row]   = (float)pd;
        }
    }
}

// ---------------------------------------------------------------------------
// kernB (carried from R8, passed): step-0 B with diag fold.
// si' = x@Ws^T + b_self - scale*pdm*round_bf16(yhat); yT0; aw.
// ---------------------------------------------------------------------------
__global__ __launch_bounds__(256) void kernB(
    const float* __restrict__ x,
    const unsigned short* __restrict__ wsb, const unsigned short* __restrict__ wpb,
    const float* __restrict__ w_nw, const float* __restrict__ b_nw,
    const float* __restrict__ b_self,
    const float* __restrict__ scale_g, const float* __restrict__ pdm_g,
    float* __restrict__ si_out, unsigned short* __restrict__ yT_out,
    float* __restrict__ aw_out)
{
    __shared__ unsigned short xt[64*32];
    __shared__ unsigned short wst[128*32];
    __shared__ unsigned short wpt[128*32];
    __shared__ float wnw_l[DD];
    __shared__ float red[256];
    __shared__ float dw_l[64];
    __shared__ float scl_l[64];
    __shared__ float pdm_l[64];
    __shared__ unsigned short ytl[128*72];

    const int n0 = blockIdx.x * 64;
    const int t  = threadIdx.x;
    const int b  = n0 >> 11;
    const int nb = n0 & (NN - 1);

    if (t < DD) wnw_l[t] = w_nw[t];
    if (t >= 128 && t < 192) { scl_l[t-128] = scale_g[n0 + t - 128]; }
    if (t >= 192)            { pdm_l[t-192] = pdm_g[n0 + t - 192]; }
    __syncthreads();

    const int wave = t >> 6, lane = t & 63;
    const int wm = wave >> 1, wn = wave & 1;
    const int quad = lane >> 4, l16 = lane & 15;

    const int n_loc = t >> 2, dq = t & 3;
    const int we = t >> 1,   wh = t & 1;

    f32x4 accs[2][4] = {}; f32x4 accp[2][4] = {};
    float dwpart = 0.f;

    #pragma unroll
    for (int kk = 0; kk < 4; ++kk) {
        const int k0 = kk * 32;
        {
            const float* xs = x + (size_t)(n0 + n_loc) * DD + k0 + dq * 8;
            f32x4 a = *(const f32x4*)xs;
            f32x4 c = *(const f32x4*)(xs + 4);
            const float* wv = &wnw_l[k0 + dq * 8];
            dwpart += a.x*wv[0] + a.y*wv[1] + a.z*wv[2] + a.w*wv[3]
                    + c.x*wv[4] + c.y*wv[5] + c.z*wv[6] + c.w*wv[7];
            unsigned q0 = f2bf(a.x) | ((unsigned)f2bf(a.y) << 16);
            unsigned q1 = f2bf(a.z) | ((unsigned)f2bf(a.w) << 16);
            unsigned q2 = f2bf(c.x) | ((unsigned)f2bf(c.y) << 16);
            unsigned q3 = f2bf(c.z) | ((unsigned)f2bf(c.w) << 16);
            i32x4 pw = {(int)q0,(int)q1,(int)q2,(int)q3};
            *(i32x4*)&xt[n_loc*32 + dq*8] = pw;
        }
        {
            const unsigned short* s1 = wsb + (size_t)we * DD + k0 + wh*16;
            const unsigned short* s2 = wpb + (size_t)we * DD + k0 + wh*16;
            i32x4 a0 = *(const i32x4*)s1;
            i32x4 a1 = *(const i32x4*)(s1 + 8);
            *(i32x4*)&wst[we*32 + wh*16]     = a0;
            *(i32x4*)&wst[we*32 + wh*16 + 8] = a1;
            i32x4 c0 = *(const i32x4*)s2;
            i32x4 c1 = *(const i32x4*)(s2 + 8);
            *(i32x4*)&wpt[we*32 + wh*16]     = c0;
            *(i32x4*)&wpt[we*32 + wh*16 + 8] = c1;
        }
        __syncthreads();
        bf16x8 af[2], bs[4], bp[4];
        #pragma unroll
        for (int mt = 0; mt < 2; ++mt)
            af[mt] = *(const bf16x8*)&xt[(wm*32 + mt*16 + l16)*32 + quad*8];
        #pragma unroll
        for (int nt = 0; nt < 4; ++nt) {
            const int er = wn*64 + nt*16 + l16;
            bs[nt] = *(const bf16x8*)&wst[er*32 + quad*8];
            bp[nt] = *(const bf16x8*)&wpt[er*32 + quad*8];
        }
        #pragma unroll
        for (int mt = 0; mt < 2; ++mt)
            #pragma unroll
            for (int nt = 0; nt < 4; ++nt) {
                accs[mt][nt] = __builtin_amdgcn_mfma_f32_16x16x32_bf16(af[mt], bs[nt], accs[mt][nt], 0, 0, 0);
                accp[mt][nt] = __builtin_amdgcn_mfma_f32_16x16x32_bf16(af[mt], bp[nt], accp[mt][nt], 0, 0, 0);
            }
        __syncthreads();
    }

    red[t] = dwpart;
    __syncthreads();
    if (t < 64) {
        float s = red[4*t] + red[4*t+1] + red[4*t+2] + red[4*t+3] + b_nw[0];
        float dv = 1.f / (1.f + __expf(-s));
        dw_l[t] = dv;
        aw_out[(size_t)b * 2 * NN + nb + t] = dv;
    }
    __syncthreads();

    #pragma unroll
    for (int mt = 0; mt < 2; ++mt) {
        #pragma unroll
        for (int nt = 0; nt < 4; ++nt) {
            const int e = wn*64 + nt*16 + l16;
            const float bsv = b_self[e];
            #pragma unroll
            for (int r = 0; r < 4; ++r) {
                const int nl = wm*32 + mt*16 + quad*4 + r;
                const size_t idx = (size_t)(n0 + nl) * DD + e;
                const float yv = dw_l[nl] * accp[mt][nt][r];
                const unsigned short ub = f2bf(yv);
                const float yvr = bf2f(ub);
                si_out[idx] = accs[mt][nt][r] + bsv - scl_l[nl] * pdm_l[nl] * yvr;
                ytl[e*72 + nl] = ub;
            }
        }
    }
    __syncthreads();
    {
        const int e = t >> 1, half = t & 1;
        const i32x4* src = (const i32x4*)&ytl[e*72 + half*32];
        i32x4 v0 = src[0], v1 = src[1], v2 = src[2], v3 = src[3];
        i32x4* dst = (i32x4*)(yT_out + (size_t)(b*DD + e) * NN + nb + half*32);
        dst[0] = v0; dst[1] = v1; dst[2] = v2; dst[3] = v3;
    }
}

// ---------------------------------------------------------------------------
// kernCB: FUSED C0 + B1. Grid 256 x 256 thr, 60.7KB LDS (phase-unioned) ->
// 2 blocks/CU (2x the TLP of R8's separate kernels).
//  C phase (R8 kernC4 structure verbatim): acc = Ptilde @ yhat0 from yT0;
//    x = relu(sip0 + scale*acc) computed IN REGISTERS — never written to
//    global. Epilogue stores x as bf16 into per-kk LDS (xt4, the proven
//    2-way-conflict-free [kk][row][32] layout) + dw partials into red.
//  dw: 8KB LDS reduce (different f32 sum order than B0 — tiny vs threshold).
//  B phase (R8 kernB_body structure): GEMMs from xt4 + staged weights;
//    diag-folded si'1, yT1, aw1.
// Per-block fusion is exact: C's 64-row output tile == B's 64-row input tile.
// LDS union timeline: pPk dead after C K-loop -> xt4/red overlay;
// accL dead after C epilogue -> wst/wpt/ytl overlay.
// ---------------------------------------------------------------------------
#define OFF_SCL   0u
#define OFF_PDM   256u
#define OFF_WNW   512u
#define OFF_DW    1024u
#define OFF_A     1280u                 // pPk (17408) -> xt4 (16384) + red
#define OFF_XT4   1280u
#define OFF_RED   (1280u + 16384u)     // 17664, 8KB
#define OFF_B     25856u                // accL (32768) -> wst/wpt/ytl
#define OFF_WST   25856u
#define OFF_WPT   (25856u + 8192u)
#define OFF_YTL   (25856u + 16384u)    // 18432B
#define SMEM_CB   60672u

__global__ __launch_bounds__(256) void kernCB(
    const unsigned* __restrict__ pk,
    const float* __restrict__ scale_g, const float* __restrict__ pdm_g,
    const unsigned short* __restrict__ yT0,
    float* si,                               // in: si'0 ; out: si'1 (same rows)
    const unsigned short* __restrict__ wsb, const unsigned short* __restrict__ wpb,
    const float* __restrict__ w_nw, const float* __restrict__ b_nw,
    const float* __restrict__ b_self,
    unsigned short* __restrict__ yT1,
    float* __restrict__ aw1)                 // aw + NN already applied
{
    __shared__ char smem[SMEM_CB];
    float*          scl_l = (float*)(smem + OFF_SCL);
    float*          pdm_l = (float*)(smem + OFF_PDM);
    float*          wnw_l = (float*)(smem + OFF_WNW);
    float*          dw_l  = (float*)(smem + OFF_DW);
    unsigned*       pPk   = (unsigned*)(smem + OFF_A);
    unsigned short* xt4   = (unsigned short*)(smem + OFF_XT4);
    float*          red   = (float*)(smem + OFF_RED);
    f32x4*          accL  = (f32x4*)(smem + OFF_B);       // [2][16][64]
    unsigned short* wst   = (unsigned short*)(smem + OFF_WST);
    unsigned short* wpt   = (unsigned short*)(smem + OFF_WPT);
    unsigned short* ytl   = (unsigned short*)(smem + OFF_YTL);

    const int t  = threadIdx.x;
    const int b  = blockIdx.x & 7;          // XCD-aware batch mapping
    const int i0 = (blockIdx.x >> 3) * 64;  // 0..1984
    const size_t rg0 = (size_t)b * NN + i0;

    // ---- stage: pPk, scale/pdm, w_nw ----
    #pragma unroll
    for (int r = 0; r < 4; ++r) {
        const int u   = r * 256 + t;
        const int row = u >> 4;
        const int wq  = (u & 15) * 4;
        i32x4 v = *(const i32x4*)(pk + (rg0 + row) * 64 + wq);
        *(i32x4*)&pPk[row * 68 + wq] = v;
    }
    if (t < 64)                   scl_l[t]      = scale_g[rg0 + t];
    else if (t < 128)             pdm_l[t-64]   = pdm_g[rg0 + t - 64];
    else                          wnw_l[t-128]  = w_nw[t-128];
    __syncthreads();

    const int wave = t >> 6, lane = t & 63;
    const int kh = wave >> 1, eh = wave & 1;
    const int quad = lane >> 4, l16 = lane & 15;
    const unsigned short* yTb = yT0 + (size_t)b * DD * NN;

    // ---- C K-loop (R8 kernC4 verbatim) ----
    f32x4 acc[4][4] = {};
    #pragma unroll 4
    for (int ks = 0; ks < 32; ++ks) {
        const int kk = kh * 32 + ks;
        bf16x8 bfr[4];
        #pragma unroll
        for (int nt = 0; nt < 4; ++nt) {
            const int e = eh*64 + nt*16 + l16;
            bfr[nt] = *(const bf16x8*)(yTb + (size_t)e * NN + kk*32 + quad*8);
        }
        bf16x8 af[4];
        #pragma unroll
        for (int mt = 0; mt < 4; ++mt) {
            const unsigned w = pPk[(mt*16 + l16) * 68 + kk];
            const unsigned by = (w >> (quad * 8)) & 0xFFu;
            i32x4 ex;
            ex.x = (int)((((by &   1u) << 7) + ((by &   2u) << 22)) * 0x7Fu);
            ex.y = (int)((((by &   4u) << 5) + ((by &   8u) << 20)) * 0x7Fu);
            ex.z = (int)((((by &  16u) << 3) + ((by &  32u) << 18)) * 0x7Fu);
            ex.w = (int)((((by &  64u) << 1) + ((by & 128u) << 16)) * 0x7Fu);
            union { i32x4 i; bf16x8 h; } cv; cv.i = ex;
            af[mt] = cv.h;
        }
        #pragma unroll
        for (int mt = 0; mt < 4; ++mt)
            #pragma unroll
            for (int nt = 0; nt < 4; ++nt)
                acc[mt][nt] = __builtin_amdgcn_mfma_f32_16x16x32_bf16(af[mt], bfr[nt], acc[mt][nt], 0, 0, 0);
    }

    __syncthreads();                         // K-loops done; pPk dead
    if (kh == 1) {
        #pragma unroll
        for (int mt = 0; mt < 4; ++mt)
            #pragma unroll
            for (int nt = 0; nt < 4; ++nt)
                accL[(eh*16 + mt*4 + nt)*64 + lane] = acc[mt][nt];
    }
    __syncthreads();

    // ---- C epilogue (kh==0): x in regs -> xt4 (bf16, per-kk) + dw partials
    if (kh == 0) {
        #pragma unroll
        for (int mt = 0; mt < 4; ++mt) {
            float part[4] = {0.f, 0.f, 0.f, 0.f};
            #pragma unroll
            for (int nt = 0; nt < 4; ++nt) {
                f32x4 o = accL[(eh*16 + mt*4 + nt)*64 + lane];
                const int e = eh*64 + nt*16 + l16;
                const float wv = wnw_l[e];
                #pragma unroll
                for (int r = 0; r < 4; ++r) {
                    const int row = mt*16 + quad*4 + r;
                    const size_t idx = (rg0 + row) * DD + e;
                    float xv = si[idx] + scl_l[row] * (acc[mt][nt][r] + o[r]);
                    xv = fmaxf(xv, 0.f);
                    xt4[((e >> 5) * 64 + row) * 32 + (e & 31)] = f2bf(xv);
                    part[r] += xv * wv;
                }
            }
            #pragma unroll
            for (int r = 0; r < 4; ++r) {
                const int row = mt*16 + quad*4 + r;
                red[row * 32 + eh*16 + l16] = part[r];
            }
        }
    }
    __syncthreads();                         // accL dead after this

    if (t < 64) {
        float s = b_nw[0];
        #pragma unroll 8
        for (int c = 0; c < 32; ++c) s += red[t * 32 + c];
        float dv = 1.f / (1.f + __expf(-s));
        dw_l[t] = dv;
        aw1[(size_t)b * 2 * NN + i0 + t] = dv;
    }
    __syncthreads();

    // ---- B phase (R8 kernB_body structure; x from xt4, dw from dw_l) ----
    const int wm = kh, wn = eh;              // same decode, B-phase names
    const int we = t >> 1, wh = t & 1;

    f32x4 accs[2][4] = {}; f32x4 accp[2][4] = {};

    #pragma unroll
    for (int kk = 0; kk < 4; ++kk) {
        const int k0 = kk * 32;
        {
            const unsigned short* s1 = wsb + (size_t)we * DD + k0 + wh*16;
            const unsigned short* s2 = wpb + (size_t)we * DD + k0 + wh*16;
            i32x4 a0 = *(const i32x4*)s1;
            i32x4 a1 = *(const i32x4*)(s1 + 8);
            *(i32x4*)&wst[we*32 + wh*16]     = a0;
            *(i32x4*)&wst[we*32 + wh*16 + 8] = a1;
            i32x4 c0 = *(const i32x4*)s2;
            i32x4 c1 = *(const i32x4*)(s2 + 8);
            *(i32x4*)&wpt[we*32 + wh*16]     = c0;
            *(i32x4*)&wpt[we*32 + wh*16 + 8] = c1;
        }
        __syncthreads();
        bf16x8 af[2], bs[4], bp[4];
        #pragma unroll
        for (int mt = 0; mt < 2; ++mt)
            af[mt] = *(const bf16x8*)&xt4[(kk*64 + wm*32 + mt*16 + l16)*32 + quad*8];
        #pragma unroll
        for (int nt = 0; nt < 4; ++nt) {
            const int er = wn*64 + nt*16 + l16;
            bs[nt] = *(const bf16x8*)&wst[er*32 + quad*8];
            bp[nt] = *(const bf16x8*)&wpt[er*32 + quad*8];
        }
        #pragma unroll
        for (int mt = 0; mt < 2; ++mt)
            #pragma unroll
            for (int nt = 0; nt < 4; ++nt) {
                accs[mt][nt] = __builtin_amdgcn_mfma_f32_16x16x32_bf16(af[mt], bs[nt], accs[mt][nt], 0, 0, 0);
                accp[mt][nt] = __builtin_amdgcn_mfma_f32_16x16x32_bf16(af[mt], bp[nt], accp[mt][nt], 0, 0, 0);
            }
        __syncthreads();
    }

    #pragma unroll
    for (int mt = 0; mt < 2; ++mt) {
        #pragma unroll
        for (int nt = 0; nt < 4; ++nt) {
            const int e = wn*64 + nt*16 + l16;
            const float bsv = b_self[e];
            #pragma unroll
            for (int r = 0; r < 4; ++r) {
                const int nl = wm*32 + mt*16 + quad*4 + r;
                const size_t idx = (rg0 + nl) * DD + e;
                const float yv = dw_l[nl] * accp[mt][nt][r];
                const unsigned short ub = f2bf(yv);
                const float yvr = bf2f(ub);
                si[idx] = accs[mt][nt][r] + bsv - scl_l[nl] * pdm_l[nl] * yvr;
                ytl[e*72 + nl] = ub;
            }
        }
    }
    __syncthreads();
    {
        const int e = t >> 1, half = t & 1;
        const i32x4* src = (const i32x4*)&ytl[e*72 + half*32];
        i32x4 v0 = src[0], v1 = src[1], v2 = src[2], v3 = src[3];
        i32x4* dst = (i32x4*)(yT1 + (size_t)(b*DD + e) * NN + i0 + half*32);
        dst[0] = v0; dst[1] = v1; dst[2] = v2; dst[3] = v3;
    }
}

// ---------------------------------------------------------------------------
// kernC4 (carried from R8, passed): final C — x_out = relu(si' + scale*agg).
// ---------------------------------------------------------------------------
__global__ __launch_bounds__(256) void kernC4(
    const unsigned* __restrict__ pk,
    const float* __restrict__ scale_g,
    const unsigned short* __restrict__ yT,
    const float* __restrict__ sip,
    float* __restrict__ x_out)
{
    __shared__ unsigned pPk[64 * 68];
    __shared__ float scale_l[64];
    __shared__ f32x4 accL[2][16][64];

    const int t  = threadIdx.x;
    const int b  = blockIdx.x & 7;
    const int i0 = (blockIdx.x >> 3) * 64;
    const size_t rg0 = (size_t)b * NN + i0;

    #pragma unroll
    for (int r = 0; r < 4; ++r) {
        const int u   = r * 256 + t;
        const int row = u >> 4;
        const int wq  = (u & 15) * 4;
        i32x4 v = *(const i32x4*)(pk + (rg0 + row) * 64 + wq);
        *(i32x4*)&pPk[row * 68 + wq] = v;
    }
    if (t < 64) scale_l[t] = scale_g[rg0 + t];
    __syncthreads();

    const int wave = t >> 6, lane = t & 63;
    const int kh = wave >> 1, eh = wave & 1;
    const int quad = lane >> 4, l16 = lane & 15;
    const unsigned short* yTb = yT + (size_t)b * DD * NN;

    f32x4 acc[4][4] = {};

    #pragma unroll 4
    for (int ks = 0; ks < 32; ++ks) {
        const int kk = kh * 32 + ks;
        bf16x8 bfr[4];
        #pragma unroll
        for (int nt = 0; nt < 4; ++nt) {
            const int e = eh*64 + nt*16 + l16;
            bfr[nt] = *(const bf16x8*)(yTb + (size_t)e * NN + kk*32 + quad*8);
        }
        bf16x8 af[4];
        #pragma unroll
        for (int mt = 0; mt < 4; ++mt) {
            const unsigned w = pPk[(mt*16 + l16) * 68 + kk];
            const unsigned by = (w >> (quad * 8)) & 0xFFu;
            i32x4 ex;
            ex.x = (int)((((by &   1u) << 7) + ((by &   2u) << 22)) * 0x7Fu);
            ex.y = (int)((((by &   4u) << 5) + ((by &   8u) << 20)) * 0x7Fu);
            ex.z = (int)((((by &  16u) << 3) + ((by &  32u) << 18)) * 0x7Fu);
            ex.w = (int)((((by &  64u) << 1) + ((by & 128u) << 16)) * 0x7Fu);
            union { i32x4 i; bf16x8 h; } cv; cv.i = ex;
            af[mt] = cv.h;
        }
        #pragma unroll
        for (int mt = 0; mt < 4; ++mt)
            #pragma unroll
            for (int nt = 0; nt < 4; ++nt)
                acc[mt][nt] = __builtin_amdgcn_mfma_f32_16x16x32_bf16(af[mt], bfr[nt], acc[mt][nt], 0, 0, 0);
    }

    __syncthreads();
    if (kh == 1) {
        #pragma unroll
        for (int mt = 0; mt < 4; ++mt)
            #pragma unroll
            for (int nt = 0; nt < 4; ++nt)
                accL[eh][mt*4 + nt][lane] = acc[mt][nt];
    }
    __syncthreads();
    if (kh == 0) {
        #pragma unroll
        for (int mt = 0; mt < 4; ++mt) {
            #pragma unroll
            for (int nt = 0; nt < 4; ++nt) {
                f32x4 o = accL[eh][mt*4 + nt][lane];
                const int e = eh*64 + nt*16 + l16;
                #pragma unroll
                for (int r = 0; r < 4; ++r) {
                    const int row = mt*16 + quad*4 + r;
                    const size_t idx = (rg0 + row) * DD + e;
                    float v = sip[idx] + scale_l[row] * (acc[mt][nt][r] + o[r]);
                    x_out[idx] = fmaxf(v, 0.f);
                }
            }
        }
    }
}

extern "C" void kernel_launch(void* const* d_in, const int* in_sizes, int n_in,
                              void* d_out, int out_size, void* d_ws, size_t ws_size,
                              hipStream_t stream) {
    const float* node   = (const float*)d_in[0];
    const int*   mask   = (const int*)  d_in[1];
    const int*   punct  = (const int*)  d_in[2];
    const float* w_nw   = (const float*)d_in[3];
    const float* b_nw   = (const float*)d_in[4];
    const float* w_self = (const float*)d_in[5];
    const float* b_self = (const float*)d_in[6];
    const float* w_punct= (const float*)d_in[7];

    float* xout = (float*)d_out;
    float* aw   = xout + (size_t)BB * NN * DD;

    char* w = (char*)d_ws;
    float*          si   = (float*)w;                               // 8 MB (si')
    unsigned short* yT0  = (unsigned short*)(w + (12u << 20));      // 4 MB
    unsigned*       pk   = (unsigned*)(w + (16u << 20));            // 4 MB
    float*          scl  = (float*)(w + (20u << 20));               // 64 KB
    float*          pdm  = (float*)(w + (20u << 20) + (64u << 10)); // 64 KB
    unsigned short* wsb  = (unsigned short*)(w + (21u << 20));      // 32 KB
    unsigned short* wpb  = (unsigned short*)(w + (21u << 20) + (32u << 10)); // 32 KB
    unsigned short* yT1  = (unsigned short*)(w + (24u << 20));      // 4 MB

    kernP3<<<dim3(2064), dim3(256), 0, stream>>>(punct, mask, w_self, w_punct,
                                                 pk, scl, pdm, wsb, wpb);
    kernB <<<dim3(256),  dim3(256), 0, stream>>>(node, wsb, wpb, w_nw, b_nw,
                                                 b_self, scl, pdm, si, yT0, aw);
    kernCB<<<dim3(256),  dim3(256), 0, stream>>>(pk, scl, pdm, yT0, si,
                                                 wsb, wpb, w_nw, b_nw, b_self,
                                                 yT1, aw + NN);
    kernC4<<<dim3(256),  dim3(256), 0, stream>>>(pk, scl, yT1, si, xout);
}